// Round 3
// baseline (231.563 us; speedup 1.0000x reference)
//
#include <hip/hip_runtime.h>

#define MA 64
#define F 128
#define NF 16
#define HID 512
#define LDU 136   // u / staged-h row stride (bf16 elems)
#define LDT 72    // hT / w row stride
#define LDT1 520  // t1 half-buffer row stride

typedef float  float4v __attribute__((ext_vector_type(4)));
typedef short  short8  __attribute__((ext_vector_type(8)));

// pack two fp32 -> (bf16(y)<<16)|bf16(x), round-half-up via +0x8000 then v_perm
static __device__ __forceinline__ unsigned int pack2bf(float x, float y) {
    unsigned int a = __float_as_uint(x) + 0x8000u;
    unsigned int b = __float_as_uint(y) + 0x8000u;
    return __builtin_amdgcn_perm(b, a, 0x07060302u);
}
static __device__ __forceinline__ unsigned short f2bf1(float x) {
    return (unsigned short)((__float_as_uint(x) + 0x8000u) >> 16);
}

// ---- Pack W1 as A-frags of W1^T, W2 as A-frags of W2^T. Direct global gather:
// each W1/W2 element read exactly once (16-lane groups read contiguous 64B).
// A-frag (16x16x32): lane l holds A[m0+(l&15)][k0+(l>>4)*8+j], j=0..7.
__global__ void pack_frags(const float* __restrict__ W1, const float* __restrict__ W2,
                           unsigned short* __restrict__ w1p, unsigned short* __restrict__ w2p) {
    int gid  = blockIdx.x * 4 + (threadIdx.x >> 6);
    int lane = threadIdx.x & 63;
    int kq   = (lane >> 4) * 8;
    int arow = lane & 15;
    float v[8];
    if (gid < 68 * 32) {                       // W1: kt (68 over K=2176) x jt (32 over 512)
        int kt = gid >> 5, jt = gid & 31;
        const float* base = W1 + (size_t)(kt * 32 + kq) * HID + jt * 16 + arow;
        #pragma unroll
        for (int j = 0; j < 8; j++) v[j] = base[j * HID];
        uint4 o = { pack2bf(v[0], v[1]), pack2bf(v[2], v[3]),
                    pack2bf(v[4], v[5]), pack2bf(v[6], v[7]) };
        *(uint4*)(w1p + (size_t)gid * 512 + lane * 8) = o;
    } else {                                   // W2: kt (16 over J=512) x mt (8 over 128)
        int g2 = gid - 68 * 32;
        int kt = g2 >> 3, mt = g2 & 7;
        const float* base = W2 + (size_t)(kt * 32 + kq) * F + mt * 16 + arow;
        #pragma unroll
        for (int j = 0; j < 8; j++) v[j] = base[j * F];
        uint4 o = { pack2bf(v[0], v[1]), pack2bf(v[2], v[3]),
                    pack2bf(v[4], v[5]), pack2bf(v[6], v[7]) };
        *(uint4*)(w2p + (size_t)g2 * 512 + lane * 8) = o;
    }
}

// ---- Main fused kernel: one block per molecule, 512 threads = 8 waves ----
__launch_bounds__(512, 4)
__global__ void node_conv_mfma(const int* __restrict__ z, const float* __restrict__ rr,
        const float* __restrict__ h, const float* __restrict__ dist,
        const float* __restrict__ wid, const float* __restrict__ b1,
        const float* __restrict__ b2,
        const unsigned short* __restrict__ w1p, const unsigned short* __restrict__ w2p,
        float* __restrict__ out) {
    const int n = blockIdx.x;
    const int tid = threadIdx.x;
    const int lane = tid & 63;
    const int wave = tid >> 6;
    const int arow = lane & 15;
    const int quad = lane >> 4;
    const int kgrp = quad * 8;

    // LDS: hT 128x72 | wL 64x72 | ub0 64x136 | ub1 64x136 = 31232 elems = 62464 B
    // t1 (32x520 = 33280 B) overlays from base during GEMM2.
    __shared__ __attribute__((aligned(16))) unsigned short lds[31232];
    unsigned short* hT  = lds;
    unsigned short* wL  = lds + 9216;
    unsigned short* ub0 = lds + 13824;
    unsigned short* ub1 = lds + 22528;
    unsigned short* t1  = lds;
    __shared__ float r_lds[MA][4];             // xyz + mask

    // ---- z / r passthrough + r/mask staging ----
    {
        int N = gridDim.x;
        if (tid < MA) {
            int zi = z[n * MA + tid];
            out[(size_t)n * MA + tid] = (float)zi;
            r_lds[tid][0] = rr[(n * MA + tid) * 3 + 0];
            r_lds[tid][1] = rr[(n * MA + tid) * 3 + 1];
            r_lds[tid][2] = rr[(n * MA + tid) * 3 + 2];
            r_lds[tid][3] = (zi > -1) ? 1.0f : 0.0f;
        }
        if (tid < 3 * MA) out[(size_t)N * MA + (size_t)n * 3 * MA + tid] = rr[(size_t)n * 3 * MA + tid];
    }

    const float* hg = h + (size_t)n * MA * F;
    // ---- pass A: h -> ub0 row-major (coalesced read, conflict-free b64 writes) ----
    for (int i = tid; i < MA * F / 4; i += 512) {
        float4 v = ((const float4*)hg)[i];
        int a = i >> 5, c4 = (i & 31) * 4;
        uint2 pv = { pack2bf(v.x, v.y), pack2bf(v.z, v.w) };
        *(uint2*)&ub0[a * LDU + c4] = pv;
    }
    // ---- pass B: h -> hT (transposed read; row-contiguous b16 writes, conflict-free) ----
    {
        int a = tid & 63, cb = tid >> 6;
        #pragma unroll
        for (int it = 0; it < 4; it++) {
            int c0 = cb * 16 + it * 4;
            float4 v = *(const float4*)&hg[a * F + c0];
            hT[(c0 + 0) * LDT + a] = f2bf1(v.x);
            hT[(c0 + 1) * LDT + a] = f2bf1(v.y);
            hT[(c0 + 2) * LDT + a] = f2bf1(v.z);
            hT[(c0 + 3) * LDT + a] = f2bf1(v.w);
        }
    }
    __syncthreads();

    // ---- per-thread pairwise distances (hoisted) ----
    const int wa = tid >> 3;
    const int wb0 = (tid & 7) * 8;
    float dpre[8], pm[8];
    {
        float ax = r_lds[wa][0], ay = r_lds[wa][1], az = r_lds[wa][2];
        float am5 = 5.0f * r_lds[wa][3];
        #pragma unroll
        for (int j = 0; j < 8; j++) {
            float dx = ax - r_lds[wb0 + j][0];
            float dy = ay - r_lds[wb0 + j][1];
            float dz = az - r_lds[wb0 + j][2];
            dpre[j] = sqrtf(dx * dx + dy * dy + dz * dz + 1e-12f);
            pm[j] = am5 * r_lds[wb0 + j][3];
        }
    }

    const float4v zf = {0.f, 0.f, 0.f, 0.f};
    float4v acc[4][4];                         // D[m=j (wave slab of 64)][n=a (64)]
    #pragma unroll
    for (int i = 0; i < 4; i++)
        #pragma unroll
        for (int jv = 0; jv < 4; jv++) acc[i][jv] = zf;

    // ---- main loop: 17 K-segments of 128; u double-buffered, 2 barriers/iter ----
    for (int f = 0; f <= NF; f++) {
        const unsigned short* ubc = (f & 1) ? ub1 : ub0;
        unsigned short* ubn = (f & 1) ? ub0 : ub1;

        // prefetch A-frags (global, L2-hot) for ks=0
        short8 afr0[4], afr1[4];
        {
            const unsigned short* p = w1p + (((size_t)(f * 4) * 32 + wave * 4) * 64 + lane) * 8;
            #pragma unroll
            for (int mt = 0; mt < 4; mt++) afr0[mt] = *(const short8*)(p + mt * 512);
        }
        // w_f exps under the load shadow
        if (f < NF) {
            float mu = dist[f];
            float isg = 1.0f / wid[f];
            float e[8];
            #pragma unroll
            for (int j = 0; j < 8; j++) {
                float t = dpre[j] - mu;
                e[j] = pm[j] * __expf(-t * t * isg);
            }
            uint4 wp = { pack2bf(e[0], e[1]), pack2bf(e[2], e[3]),
                         pack2bf(e[4], e[5]), pack2bf(e[6], e[7]) };
            *(uint4*)&wL[wa * LDT + wb0] = wp;
        }
        // GEMM1 segment f: A = w1p (pipelined), B = v-frags from LDS
        #pragma unroll
        for (int ks = 0; ks < 4; ks++) {
            short8* acur = (ks & 1) ? afr1 : afr0;
            short8* anxt = (ks & 1) ? afr0 : afr1;
            if (ks < 3) {
                const unsigned short* p = w1p + (((size_t)(f * 4 + ks + 1) * 32 + wave * 4) * 64 + lane) * 8;
                #pragma unroll
                for (int mt = 0; mt < 4; mt++) anxt[mt] = *(const short8*)(p + mt * 512);
            }
            short8 bfr[4];
            #pragma unroll
            for (int at = 0; at < 4; at++)
                bfr[at] = *(const short8*)&ubc[(at * 16 + arow) * LDU + ks * 32 + kgrp];
            #pragma unroll
            for (int mt = 0; mt < 4; mt++)
                #pragma unroll
                for (int at = 0; at < 4; at++)
                    acc[mt][at] = __builtin_amdgcn_mfma_f32_16x16x32_bf16(acur[mt], bfr[at], acc[mt][at], 0, 0, 0);
        }
        __syncthreads();                       // wL visible; ubn free (readers were iter f-1)

        if (f < NF) {
            // u_{f+1}^T = hT @ w^T : A = hT (m=c, wave's 16-slab), B = wL (n=a)
            float4v ud[4];
            #pragma unroll
            for (int at = 0; at < 4; at++) ud[at] = zf;
            #pragma unroll
            for (int ks2 = 0; ks2 < 2; ks2++) {
                short8 ah = *(const short8*)&hT[(wave * 16 + arow) * LDT + ks2 * 32 + kgrp];
                #pragma unroll
                for (int at = 0; at < 4; at++) {
                    short8 bw = *(const short8*)&wL[(at * 16 + arow) * LDT + ks2 * 32 + kgrp];
                    ud[at] = __builtin_amdgcn_mfma_f32_16x16x32_bf16(ah, bw, ud[at], 0, 0, 0);
                }
            }
            // D lane holds u[a = at*16+arow][c = wave*16+quad*4 + r] -> contiguous b64
            #pragma unroll
            for (int at = 0; at < 4; at++) {
                uint2 pv = { pack2bf(ud[at][0], ud[at][1]), pack2bf(ud[at][2], ud[at][3]) };
                *(uint2*)&ubn[(at * 16 + arow) * LDU + wave * 16 + quad * 4] = pv;
            }
            __syncthreads();                   // u_{f+1} visible; wL free
        }
    }

    // ---- GEMM2: out = h + 0.1*mask*(silu(t1) @ W2 + b2), two 32-atom halves ----
    float4 b1v[4];
    #pragma unroll
    for (int mt = 0; mt < 4; mt++)
        b1v[mt] = *(const float4*)&b1[wave * 64 + mt * 16 + quad * 4];
    float* outh = out + (size_t)gridDim.x * MA * 4 + (size_t)n * MA * F;

    for (int hh = 0; hh < 2; hh++) {
        if (hh) __syncthreads();               // half-0 covered by loop's final barrier
        // write silu(t1) rows a in [hh*32, hh*32+32): contiguous b64 per lane
        #pragma unroll
        for (int mt = 0; mt < 4; mt++) {
            #pragma unroll
            for (int ai = 0; ai < 2; ai++) {
                int at = hh * 2 + ai;
                float xs[4];
                #pragma unroll
                for (int r = 0; r < 4; r++) {
                    float x = acc[mt][at][r] + ((const float*)&b1v[mt])[r];
                    xs[r] = x / (1.0f + __expf(-x));
                }
                uint2 pv = { pack2bf(xs[0], xs[1]), pack2bf(xs[2], xs[3]) };
                *(uint2*)&t1[(ai * 16 + arow) * LDT1 + wave * 64 + mt * 16 + quad * 4] = pv;
            }
        }
        __syncthreads();

        float4v g2[2] = {zf, zf};
        for (int ks = 0; ks < 16; ks++) {
            short8 aw2 = *(const short8*)(w2p + ((size_t)(ks * 8 + wave) * 64 + lane) * 8);
            #pragma unroll
            for (int n2 = 0; n2 < 2; n2++) {
                short8 bt = *(const short8*)&t1[(n2 * 16 + arow) * LDT1 + ks * 32 + kgrp];
                g2[n2] = __builtin_amdgcn_mfma_f32_16x16x32_bf16(aw2, bt, g2[n2], 0, 0, 0);
            }
        }
        // D[m=c][n=a]: lane -> a = hh*32+n2*16+arow, c = wave*16+quad*4 + r
        #pragma unroll
        for (int n2 = 0; n2 < 2; n2++) {
            int a = hh * 32 + n2 * 16 + arow;
            int c0 = wave * 16 + quad * 4;
            float m = r_lds[a][3] * 0.1f;
            float4 hv = *(const float4*)&hg[a * F + c0];
            float4 b2v = *(const float4*)&b2[c0];
            float4 res;
            res.x = hv.x + (g2[n2][0] + b2v.x) * m;
            res.y = hv.y + (g2[n2][1] + b2v.y) * m;
            res.z = hv.z + (g2[n2][2] + b2v.z) * m;
            res.w = hv.w + (g2[n2][3] + b2v.w) * m;
            *(float4*)&outh[(size_t)a * F + c0] = res;
        }
    }
}

extern "C" void kernel_launch(void* const* d_in, const int* in_sizes, int n_in,
                              void* d_out, int out_size, void* d_ws, size_t ws_size,
                              hipStream_t stream) {
    const int*   z    = (const int*)d_in[0];
    const float* rr   = (const float*)d_in[1];
    const float* h    = (const float*)d_in[2];
    const float* dist = (const float*)d_in[3];
    const float* wid  = (const float*)d_in[4];
    const float* W1   = (const float*)d_in[5];
    const float* b1   = (const float*)d_in[6];
    const float* W2   = (const float*)d_in[7];
    const float* b2   = (const float*)d_in[8];
    float* out = (float*)d_out;

    int N = in_sizes[0] / MA;                              // 512 molecules

    unsigned short* w1p = (unsigned short*)d_ws;           // 68*32*512 = 1,114,112 bf16
    unsigned short* w2p = w1p + (size_t)68 * 32 * 512;     // 128*512   = 65,536 bf16

    pack_frags<<<576, 256, 0, stream>>>(W1, W2, w1p, w2p);
    node_conv_mfma<<<N, 512, 0, stream>>>(z, rr, h, dist, wid, b1, b2, w1p, w2p, out);
}

// Round 4
// 180.499 us; speedup vs baseline: 1.2829x; 1.2829x over previous
//
#include <hip/hip_runtime.h>

#define MA 64
#define F 128
#define NF 16
#define HID 512
#define LDU 136   // u / staged-h row stride (bf16 elems)
#define LDT 72    // w row stride
#define LDT1 520  // t1 half-buffer row stride

typedef float  float4v __attribute__((ext_vector_type(4)));
typedef short  short8  __attribute__((ext_vector_type(8)));

// pack two fp32 -> (bf16(y)<<16)|bf16(x), round-half-up via +0x8000 then v_perm
static __device__ __forceinline__ unsigned int pack2bf(float x, float y) {
    unsigned int a = __float_as_uint(x) + 0x8000u;
    unsigned int b = __float_as_uint(y) + 0x8000u;
    return __builtin_amdgcn_perm(b, a, 0x07060302u);
}
static __device__ __forceinline__ unsigned short f2bf1(float x) {
    return (unsigned short)((__float_as_uint(x) + 0x8000u) >> 16);
}

// ---- Pack W1 as A-frags of W1^T, W2 as A-frags of W2^T (direct global gather).
// A-frag (16x16x32): lane l holds A[m0+(l&15)][k0+(l>>4)*8+j], j=0..7.
__global__ void pack_frags(const float* __restrict__ W1, const float* __restrict__ W2,
                           unsigned short* __restrict__ w1p, unsigned short* __restrict__ w2p) {
    int gid  = blockIdx.x * 4 + (threadIdx.x >> 6);
    int lane = threadIdx.x & 63;
    int kq   = (lane >> 4) * 8;
    int arow = lane & 15;
    float v[8];
    if (gid < 68 * 32) {                       // W1: kt (68 over K=2176) x jt (32 over 512)
        int kt = gid >> 5, jt = gid & 31;
        const float* base = W1 + (size_t)(kt * 32 + kq) * HID + jt * 16 + arow;
        #pragma unroll
        for (int j = 0; j < 8; j++) v[j] = base[j * HID];
        uint4 o = { pack2bf(v[0], v[1]), pack2bf(v[2], v[3]),
                    pack2bf(v[4], v[5]), pack2bf(v[6], v[7]) };
        *(uint4*)(w1p + (size_t)gid * 512 + lane * 8) = o;
    } else {                                   // W2: kt (16 over J=512) x mt (8 over 128)
        int g2 = gid - 68 * 32;
        int kt = g2 >> 3, mt = g2 & 7;
        const float* base = W2 + (size_t)(kt * 32 + kq) * F + mt * 16 + arow;
        #pragma unroll
        for (int j = 0; j < 8; j++) v[j] = base[j * F];
        uint4 o = { pack2bf(v[0], v[1]), pack2bf(v[2], v[3]),
                    pack2bf(v[4], v[5]), pack2bf(v[6], v[7]) };
        *(uint4*)(w2p + (size_t)g2 * 512 + lane * 8) = o;
    }
}

// ---- Main fused kernel: TWO molecules per block, 512 threads = 8 waves ----
// LDS (bf16 elems): ub0 @0 (8704) | ub1 @8704 (8704) | wL0 @17408 (4608) | wL1 @22016 (4608)
// t1 (32x520 = 16640 elems) overlays ub0/ub1 during GEMM2. Total 53248 B + r_lds 2 KB.
__launch_bounds__(512, 2)
__global__ void node_conv_mfma(const int* __restrict__ z, const float* __restrict__ rr,
        const float* __restrict__ h, const float* __restrict__ dist,
        const float* __restrict__ wid, const float* __restrict__ b1,
        const float* __restrict__ b2,
        const unsigned short* __restrict__ w1p, const unsigned short* __restrict__ w2p,
        float* __restrict__ out) {
    const int nb = blockIdx.x;                 // molecules 2nb, 2nb+1
    const int tid = threadIdx.x;
    const int lane = tid & 63;
    const int wave = tid >> 6;
    const int arow = lane & 15;
    const int quad = lane >> 4;
    const int kgrp = quad * 8;

    __shared__ __attribute__((aligned(16))) unsigned short lds[26624];
    __shared__ float r_lds[2][MA][4];          // xyz + mask per molecule

    const int N = gridDim.x * 2;
    const int n0 = nb * 2;
    const float* hg0 = h + (size_t)n0 * MA * F;

    // ---- z / r passthrough + r/mask staging (both molecules) ----
    if (tid < 2 * MA) {
        int zi = z[n0 * MA + tid];
        out[(size_t)n0 * MA + tid] = (float)zi;
        int mol = tid >> 6, a = tid & 63;
        r_lds[mol][a][0] = rr[(n0 * MA + tid) * 3 + 0];
        r_lds[mol][a][1] = rr[(n0 * MA + tid) * 3 + 1];
        r_lds[mol][a][2] = rr[(n0 * MA + tid) * 3 + 2];
        r_lds[mol][a][3] = (zi > -1) ? 1.0f : 0.0f;
    }
    if (tid < 2 * MA * 3)
        out[(size_t)N * MA + (size_t)n0 * MA * 3 + tid] = rr[(size_t)n0 * MA * 3 + tid];

    // ---- stage h -> ub (row-major bf16, both molecules) ----
    for (int i = tid; i < 2 * MA * F / 4; i += 512) {
        float4 v = ((const float4*)hg0)[i];
        int mol = i >> 11;                     // 2048 float4 per molecule
        int j = i & 2047;
        int a = j >> 5, c4 = (j & 31) * 4;
        uint2 pv = { pack2bf(v.x, v.y), pack2bf(v.z, v.w) };
        *(uint2*)&lds[mol * 8704 + a * LDU + c4] = pv;
    }
    // ---- hT A-fragments held in registers: lane holds h[b][c], c = wave*16+arow ----
    short8 ah[2][2];
    {
        int c = wave * 16 + arow;
        #pragma unroll
        for (int mol = 0; mol < 2; mol++) {
            const float* hm = hg0 + mol * MA * F;
            #pragma unroll
            for (int ks2 = 0; ks2 < 2; ks2++)
                #pragma unroll
                for (int j = 0; j < 8; j++)
                    ah[mol][ks2][j] = (short)f2bf1(hm[(size_t)(ks2 * 32 + kgrp + j) * F + c]);
        }
    }
    __syncthreads();

    // ---- per-thread pairwise distances, mask folded in (d+1e4 -> exp underflows to 0) ----
    const int wa = tid >> 3;
    const int wb0 = (tid & 7) * 8;
    float dpre[2][8];
    #pragma unroll
    for (int mol = 0; mol < 2; mol++) {
        float ax = r_lds[mol][wa][0], ay = r_lds[mol][wa][1], az = r_lds[mol][wa][2];
        float am = r_lds[mol][wa][3];
        #pragma unroll
        for (int j = 0; j < 8; j++) {
            float dx = ax - r_lds[mol][wb0 + j][0];
            float dy = ay - r_lds[mol][wb0 + j][1];
            float dz = az - r_lds[mol][wb0 + j][2];
            float d = sqrtf(dx * dx + dy * dy + dz * dz + 1e-12f);
            float mm = am * r_lds[mol][wb0 + j][3];
            dpre[mol][j] = d + (1.0f - mm) * 1e4f;
        }
    }

    const float4v zf = {0.f, 0.f, 0.f, 0.f};
    float4v acc[2][4][4];                      // [mol][j-tile in wave's 64-slab][a-tile]
    #pragma unroll
    for (int m = 0; m < 2; m++)
        #pragma unroll
        for (int i = 0; i < 4; i++)
            #pragma unroll
            for (int jv = 0; jv < 4; jv++) acc[m][i][jv] = zf;

    // ---- main loop: 17 K-segments of 128; single u buffer, 2 barriers/iter ----
    for (int f = 0; f <= NF; f++) {
        const unsigned short* pA = w1p + (((size_t)(f * 128) + wave * 4) * 64 + lane) * 8;
        short8 afr0[4], afr1[4];
        #pragma unroll
        for (int mt = 0; mt < 4; mt++) afr0[mt] = *(const short8*)(pA + mt * 512);

        if (f < NF) {                          // w_f exps under the load shadow
            float mu = dist[f];
            float isg = 1.0f / wid[f];
            #pragma unroll
            for (int mol = 0; mol < 2; mol++) {
                float e[8];
                #pragma unroll
                for (int j = 0; j < 8; j++) {
                    float t = dpre[mol][j] - mu;
                    e[j] = 5.0f * __expf(-t * t * isg);
                }
                uint4 wp = { pack2bf(e[0], e[1]), pack2bf(e[2], e[3]),
                             pack2bf(e[4], e[5]), pack2bf(e[6], e[7]) };
                *(uint4*)&lds[17408 + mol * 4608 + wa * LDT + wb0] = wp;
            }
        }
        // GEMM1 segment f: A = w1p frags (shared by both molecules), B = ub frags
        #pragma unroll
        for (int ks = 0; ks < 4; ks++) {
            short8* acur = (ks & 1) ? afr1 : afr0;
            short8* anxt = (ks & 1) ? afr0 : afr1;
            if (ks < 3) {
                #pragma unroll
                for (int mt = 0; mt < 4; mt++)
                    anxt[mt] = *(const short8*)(pA + (ks + 1) * 16384 + mt * 512);
            }
            short8 bfr[2][4];
            #pragma unroll
            for (int mol = 0; mol < 2; mol++)
                #pragma unroll
                for (int at = 0; at < 4; at++)
                    bfr[mol][at] = *(const short8*)&lds[mol * 8704 + (at * 16 + arow) * LDU + ks * 32 + kgrp];
            #pragma unroll
            for (int mt = 0; mt < 4; mt++)
                #pragma unroll
                for (int mol = 0; mol < 2; mol++)
                    #pragma unroll
                    for (int at = 0; at < 4; at++)
                        acc[mol][mt][at] = __builtin_amdgcn_mfma_f32_16x16x32_bf16(
                            acur[mt], bfr[mol][at], acc[mol][mt][at], 0, 0, 0);
        }
        __syncthreads();                       // B1: ub reads done; wL visible

        if (f < NF) {
            // u^T = hT @ w  (w symmetric): A = ah regs, B = wL; D -> contiguous b64 u writes
            #pragma unroll
            for (int mol = 0; mol < 2; mol++) {
                float4v ud[4];
                #pragma unroll
                for (int at = 0; at < 4; at++) ud[at] = zf;
                #pragma unroll
                for (int ks2 = 0; ks2 < 2; ks2++)
                    #pragma unroll
                    for (int at = 0; at < 4; at++) {
                        short8 bw = *(const short8*)&lds[17408 + mol * 4608 + (at * 16 + arow) * LDT + ks2 * 32 + kgrp];
                        ud[at] = __builtin_amdgcn_mfma_f32_16x16x32_bf16(ah[mol][ks2], bw, ud[at], 0, 0, 0);
                    }
                #pragma unroll
                for (int at = 0; at < 4; at++) {
                    uint2 pv = { pack2bf(ud[at][0], ud[at][1]), pack2bf(ud[at][2], ud[at][3]) };
                    *(uint2*)&lds[mol * 8704 + (at * 16 + arow) * LDU + wave * 16 + quad * 4] = pv;
                }
            }
            __syncthreads();                   // B2: u visible
        }
    }

    // ---- GEMM2: out = h + 0.1*mask*(silu(t1) @ W2 + b2); 4 half-tiles (2 mol x 2) ----
    float4 b1v[4];
    #pragma unroll
    for (int mt = 0; mt < 4; mt++)
        b1v[mt] = *(const float4*)&b1[wave * 64 + mt * 16 + quad * 4];
    float* outh0 = out + (size_t)N * MA * 4 + (size_t)n0 * MA * F;

    #pragma unroll
    for (int half = 0; half < 4; half++) {
        const int mol = half >> 1, hh = half & 1;
        if (half) __syncthreads();             // prior GEMM2 reads of t1 done
        #pragma unroll
        for (int mt = 0; mt < 4; mt++) {
            #pragma unroll
            for (int ai = 0; ai < 2; ai++) {
                const int at = hh * 2 + ai;
                float xs[4];
                #pragma unroll
                for (int r = 0; r < 4; r++) {
                    float x = acc[mol][mt][at][r] + ((const float*)&b1v[mt])[r];
                    xs[r] = x / (1.0f + __expf(-x));
                }
                uint2 pv = { pack2bf(xs[0], xs[1]), pack2bf(xs[2], xs[3]) };
                *(uint2*)&lds[(ai * 16 + arow) * LDT1 + wave * 64 + mt * 16 + quad * 4] = pv;
            }
        }
        __syncthreads();                       // t1 half visible

        float4v g2[2] = {zf, zf};
        for (int ks = 0; ks < 16; ks++) {
            short8 aw2 = *(const short8*)(w2p + ((size_t)(ks * 8 + wave) * 64 + lane) * 8);
            #pragma unroll
            for (int n2 = 0; n2 < 2; n2++) {
                short8 bt = *(const short8*)&lds[(n2 * 16 + arow) * LDT1 + ks * 32 + kgrp];
                g2[n2] = __builtin_amdgcn_mfma_f32_16x16x32_bf16(aw2, bt, g2[n2], 0, 0, 0);
            }
        }
        // D[m=c][n=a]: a = hh*32+n2*16+arow, c = wave*16+quad*4 + r
        const float* hgm = hg0 + mol * MA * F;
        float* outh = outh0 + mol * MA * F;
        #pragma unroll
        for (int n2 = 0; n2 < 2; n2++) {
            int a = hh * 32 + n2 * 16 + arow;
            int c0 = wave * 16 + quad * 4;
            float m = r_lds[mol][a][3] * 0.1f;
            float4 hv = *(const float4*)&hgm[a * F + c0];
            float4 b2v = *(const float4*)&b2[c0];
            float4 res;
            res.x = hv.x + (g2[n2][0] + b2v.x) * m;
            res.y = hv.y + (g2[n2][1] + b2v.y) * m;
            res.z = hv.z + (g2[n2][2] + b2v.z) * m;
            res.w = hv.w + (g2[n2][3] + b2v.w) * m;
            *(float4*)&outh[(size_t)a * F + c0] = res;
        }
    }
}

extern "C" void kernel_launch(void* const* d_in, const int* in_sizes, int n_in,
                              void* d_out, int out_size, void* d_ws, size_t ws_size,
                              hipStream_t stream) {
    const int*   z    = (const int*)d_in[0];
    const float* rr   = (const float*)d_in[1];
    const float* h    = (const float*)d_in[2];
    const float* dist = (const float*)d_in[3];
    const float* wid  = (const float*)d_in[4];
    const float* W1   = (const float*)d_in[5];
    const float* b1   = (const float*)d_in[6];
    const float* W2   = (const float*)d_in[7];
    const float* b2   = (const float*)d_in[8];
    float* out = (float*)d_out;

    int Nmol = in_sizes[0] / MA;                           // 512 molecules

    unsigned short* w1p = (unsigned short*)d_ws;           // 68*32*512 = 1,114,112 bf16
    unsigned short* w2p = w1p + (size_t)68 * 32 * 512;     // 128*512   = 65,536 bf16

    pack_frags<<<576, 256, 0, stream>>>(W1, W2, w1p, w2p);
    node_conv_mfma<<<Nmol / 2, 512, 0, stream>>>(z, rr, h, dist, wid, b1, b2, w1p, w2p, out);
}